// Round 6
// baseline (148.081 us; speedup 1.0000x reference)
//
#include <hip/hip_runtime.h>
#include <hip/hip_bf16.h>

// ContrastiveLoss: B=8192, D=128, 100 classes.
// loss_i = -log( max(sum_{j!=i, lab_j==lab_i} e^{s_ij},1e-8) / max(sum_{j!=i} e^{s_ij},1e-8) )
// s_ij = clip( f_hat_i . f_hat_j / 0.07, -10, 10 );  out = mean_i loss_i
//
// fb = f_hat * sqrt(log2e/0.07) in bf16 -> MFMA dot yields s/0.07*log2e directly;
// clamp at +-10*log2e (fmed3), single v_exp_f32 (exp2). Diagonal excluded exactly
// via wave-uniform tile check.
//
// R5 change: R4's 64-rows/wave spilled (VGPR demand ~180 vs 128 -> 145 MB
// scratch traffic, 131 us). Keep R3's proven 32-rows/wave no-spill shape but
// get R4's staging amortization + 2x latency hiding via 512-thread blocks:
// 8 waves share one 64 KB B-stage (256 rows/block), grid (32,32), 2 resident
// blocks/CU = 4 waves/SIMD. launch_bounds(512,4) pins allocator at 128 VGPR;
// labj packed as u16 pairs to trim pressure.

using short8  = __attribute__((ext_vector_type(8))) short;   // 8 bf16 = 4 VGPRs
using floatx4 = __attribute__((ext_vector_type(4))) float;

constexpr int   Bn = 8192;
constexpr int   Dk = 128;
constexpr int   NSLICE = 32;               // j-slices (blockIdx.x)
constexpr float PRESCALE = 4.5398160f;     // sqrt(log2(e)/0.07)
constexpr float CLAMP    = 14.4269504f;    // 10*log2(e)
constexpr float LN2      = 0.69314718056f;

// ---- kernel 1: row L2-normalize, scale, cast to bf16; also zero `out` ----
__global__ __launch_bounds__(256) void normalize_k(
    const float* __restrict__ feat, unsigned short* __restrict__ fb,
    float* __restrict__ out) {
  if (blockIdx.x == 0 && threadIdx.x == 0) *out = 0.f;   // replaces memset dispatch
  const int row  = blockIdx.x * 4 + (threadIdx.x >> 6);
  const int lane = threadIdx.x & 63;
  const float2 v = ((const float2*)(feat + (size_t)row * Dk))[lane];
  float s = v.x * v.x + v.y * v.y;
#pragma unroll
  for (int m = 1; m < 64; m <<= 1) s += __shfl_xor(s, m);
  const float inv = PRESCALE / fmaxf(sqrtf(s), 1e-8f);
  __hip_bfloat16 b0 = __float2bfloat16(v.x * inv);
  __hip_bfloat16 b1 = __float2bfloat16(v.y * inv);
  ushort2 o;
  o.x = __builtin_bit_cast(unsigned short, b0);
  o.y = __builtin_bit_cast(unsigned short, b1);
  ((ushort2*)(fb + (size_t)row * Dk))[lane] = o;
}

// ---- kernel 2: tiled F*F^T with fused exp + masked row-sum --------------
// grid: (32 j-slices, 32 i-blocks). Block = 512 thr = 8 waves.
// Block stages its 256-col B slice (64 KB) in LDS (XOR-16B-chunk swizzle);
// each wave: 32 rows x 256 cols, A frags register-resident, 16 col-tiles.
// 2 blocks/CU resident -> 4 waves/SIMD latency hiding.
__global__ __launch_bounds__(512, 4) void simloss_k(
    const unsigned short* __restrict__ fb, const int* __restrict__ labels,
    float* __restrict__ rowpos2, float* __restrict__ rowneg2) {
  __shared__ __align__(16) short Bsh[256 * Dk];   // 65536 B

  const int t     = threadIdx.x;
  const int lane  = t & 63;
  const int wave  = t >> 6;                         // [0,8)
  const int quad  = lane >> 4;
  const int lr    = lane & 15;
  const int ibase = blockIdx.y * 256 + wave * 32;   // rows [ibase, ibase+32)
  const int jbase = blockIdx.x * 256;               // cols [jbase, jbase+256)

  // ---- A fragments first (latency overlapped with staging) ---------------
  short8 A[2][4];   // [row-tile][kk]
#pragma unroll
  for (int tt = 0; tt < 2; ++tt) {
    const short* ap = (const short*)fb + (size_t)(ibase + tt * 16 + lr) * Dk + quad * 8;
#pragma unroll
    for (int kk = 0; kk < 4; ++kk) A[tt][kk] = *(const short8*)(ap + kk * 32);
  }

  // ---- stage B slice into LDS, swizzled: chunk c of row r -> c ^ (r&7) ----
  {
    const int chunk = t & 15;        // 16B chunk within a 256B row
    const int r0    = t >> 4;        // [0,32)
#pragma unroll
    for (int it = 0; it < 8; ++it) {
      const int row = r0 + it * 32;
      const short8 v = *(const short8*)((const short*)fb +
                          (size_t)(jbase + row) * Dk + chunk * 8);
      *(short8*)(Bsh + row * Dk + ((chunk ^ (row & 7)) * 8)) = v;
    }
  }

  // row labels (accumulator rows: row_in_tile = quad*4 + r)
  int li[2][4];
#pragma unroll
  for (int tt = 0; tt < 2; ++tt)
#pragma unroll
    for (int r = 0; r < 4; ++r)
      li[tt][r] = labels[ibase + tt * 16 + quad * 4 + r];

  // column labels for this lane, packed 2 tiles per reg (labels < 100 fit u16)
  int labj16[8];
#pragma unroll
  for (int j = 0; j < 8; ++j) {
    const int l0 = labels[jbase + (2 * j) * 16 + lr];
    const int l1 = labels[jbase + (2 * j + 1) * 16 + lr];
    labj16[j] = l0 | (l1 << 16);
  }

  bool dl[4];
#pragma unroll
  for (int r = 0; r < 4; ++r) dl[r] = (quad * 4 + r) == lr;

  // per-lane swizzled chunk offsets (constant across jt), in shorts
  const int sw = lr & 7;
  const int c0 = ((0 + quad) ^ sw) * 8;
  const int c1 = ((4 + quad) ^ sw) * 8;
  const int c2 = ((8 + quad) ^ sw) * 8;
  const int c3 = ((12 + quad) ^ sw) * 8;

  float pos[2][4] = {};
  float neg[2][4] = {};

  __syncthreads();

#pragma unroll
  for (int jt = 0; jt < 16; ++jt) {
    const short* bp = Bsh + (jt * 16 + lr) * Dk;
    const short8 B0 = *(const short8*)(bp + c0);
    const short8 B1 = *(const short8*)(bp + c1);
    const short8 B2 = *(const short8*)(bp + c2);
    const short8 B3 = *(const short8*)(bp + c3);

    floatx4 acc0 = {0.f, 0.f, 0.f, 0.f};
    floatx4 acc1 = {0.f, 0.f, 0.f, 0.f};
    acc0 = __builtin_amdgcn_mfma_f32_16x16x32_bf16(A[0][0], B0, acc0, 0, 0, 0);
    acc1 = __builtin_amdgcn_mfma_f32_16x16x32_bf16(A[1][0], B0, acc1, 0, 0, 0);
    acc0 = __builtin_amdgcn_mfma_f32_16x16x32_bf16(A[0][1], B1, acc0, 0, 0, 0);
    acc1 = __builtin_amdgcn_mfma_f32_16x16x32_bf16(A[1][1], B1, acc1, 0, 0, 0);
    acc0 = __builtin_amdgcn_mfma_f32_16x16x32_bf16(A[0][2], B2, acc0, 0, 0, 0);
    acc1 = __builtin_amdgcn_mfma_f32_16x16x32_bf16(A[1][2], B2, acc1, 0, 0, 0);
    acc0 = __builtin_amdgcn_mfma_f32_16x16x32_bf16(A[0][3], B3, acc0, 0, 0, 0);
    acc1 = __builtin_amdgcn_mfma_f32_16x16x32_bf16(A[1][3], B3, acc1, 0, 0, 0);

    const int j0 = jbase + jt * 16;
    const int lj = (jt & 1) ? (labj16[jt >> 1] >> 16) : (labj16[jt >> 1] & 0xffff);
    float e0, e1, e2, e3;
    // tile t=0
    e0 = __builtin_amdgcn_exp2f(__builtin_amdgcn_fmed3f(acc0[0], -CLAMP, CLAMP));
    e1 = __builtin_amdgcn_exp2f(__builtin_amdgcn_fmed3f(acc0[1], -CLAMP, CLAMP));
    e2 = __builtin_amdgcn_exp2f(__builtin_amdgcn_fmed3f(acc0[2], -CLAMP, CLAMP));
    e3 = __builtin_amdgcn_exp2f(__builtin_amdgcn_fmed3f(acc0[3], -CLAMP, CLAMP));
    if (j0 == ibase) {                 // wave-uniform: tile on diagonal
      if (dl[0]) e0 = 0.f;
      if (dl[1]) e1 = 0.f;
      if (dl[2]) e2 = 0.f;
      if (dl[3]) e3 = 0.f;
    }
    neg[0][0] += e0; neg[0][1] += e1; neg[0][2] += e2; neg[0][3] += e3;
    pos[0][0] += (li[0][0] == lj) ? e0 : 0.f;
    pos[0][1] += (li[0][1] == lj) ? e1 : 0.f;
    pos[0][2] += (li[0][2] == lj) ? e2 : 0.f;
    pos[0][3] += (li[0][3] == lj) ? e3 : 0.f;
    // tile t=1
    e0 = __builtin_amdgcn_exp2f(__builtin_amdgcn_fmed3f(acc1[0], -CLAMP, CLAMP));
    e1 = __builtin_amdgcn_exp2f(__builtin_amdgcn_fmed3f(acc1[1], -CLAMP, CLAMP));
    e2 = __builtin_amdgcn_exp2f(__builtin_amdgcn_fmed3f(acc1[2], -CLAMP, CLAMP));
    e3 = __builtin_amdgcn_exp2f(__builtin_amdgcn_fmed3f(acc1[3], -CLAMP, CLAMP));
    if (j0 == ibase + 16) {
      if (dl[0]) e0 = 0.f;
      if (dl[1]) e1 = 0.f;
      if (dl[2]) e2 = 0.f;
      if (dl[3]) e3 = 0.f;
    }
    neg[1][0] += e0; neg[1][1] += e1; neg[1][2] += e2; neg[1][3] += e3;
    pos[1][0] += (li[1][0] == lj) ? e0 : 0.f;
    pos[1][1] += (li[1][1] == lj) ? e1 : 0.f;
    pos[1][2] += (li[1][2] == lj) ? e2 : 0.f;
    pos[1][3] += (li[1][3] == lj) ? e3 : 0.f;
  }

  // reduce across the 16 lanes of a col-group (xor 1,2,4,8 stays in group);
  // unique (slice,row) writer -> plain stores, no atomics, no memset
#pragma unroll
  for (int tt = 0; tt < 2; ++tt)
#pragma unroll
    for (int r = 0; r < 4; ++r) {
      float p = pos[tt][r], n = neg[tt][r];
#pragma unroll
      for (int m = 1; m < 16; m <<= 1) {
        p += __shfl_xor(p, m);
        n += __shfl_xor(n, m);
      }
      if (lr == 0) {
        const int row = ibase + tt * 16 + quad * 4 + r;
        rowpos2[(size_t)blockIdx.x * Bn + row] = p;
        rowneg2[(size_t)blockIdx.x * Bn + row] = n;
      }
    }
}

// ---- kernel 3: sum slice partials, per-row loss, mean (distributed) ------
__global__ __launch_bounds__(256) void finalize_k(
    const float* __restrict__ rowpos2, const float* __restrict__ rowneg2,
    float* __restrict__ out) {
  const int row = blockIdx.x * 256 + threadIdx.x;
  float p = 0.f, n = 0.f;
#pragma unroll
  for (int s = 0; s < NSLICE; ++s) {       // coalesced: consecutive rows adjacent
    p += rowpos2[(size_t)s * Bn + row];
    n += rowneg2[(size_t)s * Bn + row];
  }
  p = fmaxf(p, 1e-8f);
  n = fmaxf(n, 1e-8f);
  float loss = LN2 * (__builtin_amdgcn_logf(n) - __builtin_amdgcn_logf(p));
#pragma unroll
  for (int m = 1; m < 64; m <<= 1) loss += __shfl_xor(loss, m);
  __shared__ float partial[4];
  const int lane = threadIdx.x & 63, w = threadIdx.x >> 6;
  if (lane == 0) partial[w] = loss;
  __syncthreads();
  if (threadIdx.x == 0) {
    const float s = partial[0] + partial[1] + partial[2] + partial[3];
    atomicAdd(out, s * (1.0f / (float)Bn));   // out zeroed by normalize_k
  }
}

extern "C" void kernel_launch(void* const* d_in, const int* in_sizes, int n_in,
                              void* d_out, int out_size, void* d_ws, size_t ws_size,
                              hipStream_t stream) {
  const float* feat   = (const float*)d_in[0];
  const int*   labels = (const int*)d_in[1];
  float* out = (float*)d_out;

  // ws layout: [0, 2MB) bf16 fb[8192][128]; then rowpos2[32][8192], rowneg2[32][8192]
  unsigned short* fb = (unsigned short*)d_ws;
  float* rowpos2 = (float*)((char*)d_ws + (size_t)Bn * Dk * sizeof(unsigned short));
  float* rowneg2 = rowpos2 + (size_t)NSLICE * Bn;

  normalize_k<<<Bn / 4, 256, 0, stream>>>(feat, fb, out);
  dim3 grid(NSLICE, 32);  // x = j-slice, y = i-block (256 rows each)
  simloss_k<<<grid, 512, 0, stream>>>(fb, labels, rowpos2, rowneg2);
  finalize_k<<<Bn / 256, 256, 0, stream>>>(rowpos2, rowneg2, out);
}

// Round 7
// 110.554 us; speedup vs baseline: 1.3394x; 1.3394x over previous
//
#include <hip/hip_runtime.h>
#include <hip/hip_bf16.h>

// ContrastiveLoss: B=8192, D=128, 100 classes.
// loss_i = -log( max(sum_{j!=i, lab_j==lab_i} e^{s_ij},1e-8) / max(sum_{j!=i} e^{s_ij},1e-8) )
// s_ij = clip( f_hat_i . f_hat_j / 0.07, -10, 10 );  out = mean_i loss_i
//
// fb = f_hat * sqrt(log2e/0.07) in bf16 -> MFMA dot yields s/0.07*log2e directly;
// clamp at +-10*log2e (fmed3), single v_exp_f32 (exp2). Diagonal excluded exactly
// via wave-uniform tile check.
//
// R6: R4 (64 rows/wave, VGPR=128) and R5 (512 thr, VGPR=64) both spilled
// catastrophically (90-155 MB scratch traffic) — the ROCm RA targets max
// occupancy and spills rather than keep ~100 live regs. R3's shape (256 thr,
// 64 KB LDS, 32 rows/wave) is the only proven no-spill fast config. R6 keeps
// that register shape EXACTLY but halves staging/barrier events: each block
// covers 256 rows x 256 cols, each wave doing two sequential 32-row passes
// over one staged B panel. unroll-1 pass loop + sched_barrier(0) stop the
// scheduler from hoisting pass-1 A-loads (which would recreate R4's demand).

using short8  = __attribute__((ext_vector_type(8))) short;   // 8 bf16 = 4 VGPRs
using floatx4 = __attribute__((ext_vector_type(4))) float;

constexpr int   Bn = 8192;
constexpr int   Dk = 128;
constexpr int   NSLICE = 32;               // j-slices (blockIdx.x)
constexpr float PRESCALE = 4.5398160f;     // sqrt(log2(e)/0.07)
constexpr float CLAMP    = 14.4269504f;    // 10*log2(e)
constexpr float LN2      = 0.69314718056f;

// ---- kernel 1: row L2-normalize, scale, cast to bf16; also zero `out` ----
__global__ __launch_bounds__(256) void normalize_k(
    const float* __restrict__ feat, unsigned short* __restrict__ fb,
    float* __restrict__ out) {
  if (blockIdx.x == 0 && threadIdx.x == 0) *out = 0.f;   // replaces memset dispatch
  const int row  = blockIdx.x * 4 + (threadIdx.x >> 6);
  const int lane = threadIdx.x & 63;
  const float2 v = ((const float2*)(feat + (size_t)row * Dk))[lane];
  float s = v.x * v.x + v.y * v.y;
#pragma unroll
  for (int m = 1; m < 64; m <<= 1) s += __shfl_xor(s, m);
  const float inv = PRESCALE / fmaxf(sqrtf(s), 1e-8f);
  __hip_bfloat16 b0 = __float2bfloat16(v.x * inv);
  __hip_bfloat16 b1 = __float2bfloat16(v.y * inv);
  ushort2 o;
  o.x = __builtin_bit_cast(unsigned short, b0);
  o.y = __builtin_bit_cast(unsigned short, b1);
  ((ushort2*)(fb + (size_t)row * Dk))[lane] = o;
}

// ---- kernel 2: tiled F*F^T with fused exp + masked row-sum --------------
// grid: (32 j-slices, 32 i-blocks). Block = 256 thr = 4 waves.
// Block stages its 256-col B slice (64 KB) in LDS once; each wave covers 64
// rows as TWO sequential 32-row passes (R3's exact per-pass register shape).
__global__ __launch_bounds__(256, 2) void simloss_k(
    const unsigned short* __restrict__ fb, const int* __restrict__ labels,
    float* __restrict__ rowpos2, float* __restrict__ rowneg2) {
  __shared__ __align__(16) short Bsh[256 * Dk];   // 65536 B

  const int t     = threadIdx.x;
  const int lane  = t & 63;
  const int wave  = t >> 6;                         // [0,4)
  const int quad  = lane >> 4;
  const int lr    = lane & 15;
  const int jbase = blockIdx.x * 256;               // cols [jbase, jbase+256)

  // ---- stage B slice into LDS, swizzled: chunk c of row r -> c ^ (r&7) ----
  {
    const int chunk = t & 15;        // 16B chunk within a 256B row
    const int r0    = t >> 4;        // [0,16)
#pragma unroll
    for (int it = 0; it < 16; ++it) {
      const int row = r0 + it * 16;
      const short8 v = *(const short8*)((const short*)fb +
                          (size_t)(jbase + row) * Dk + chunk * 8);
      *(short8*)(Bsh + row * Dk + ((chunk ^ (row & 7)) * 8)) = v;
    }
  }

  // column labels for this lane, packed 2 tiles per reg (labels < 100 fit u16)
  int labj16[8];
#pragma unroll
  for (int j = 0; j < 8; ++j) {
    const int l0 = labels[jbase + (2 * j) * 16 + lr];
    const int l1 = labels[jbase + (2 * j + 1) * 16 + lr];
    labj16[j] = l0 | (l1 << 16);
  }

  bool dl[4];
#pragma unroll
  for (int r = 0; r < 4; ++r) dl[r] = (quad * 4 + r) == lr;

  // per-lane swizzled chunk offsets (constant across jt), in shorts
  const int sw = lr & 7;
  const int c0 = ((0 + quad) ^ sw) * 8;
  const int c1 = ((4 + quad) ^ sw) * 8;
  const int c2 = ((8 + quad) ^ sw) * 8;
  const int c3 = ((12 + quad) ^ sw) * 8;

  __syncthreads();

#pragma unroll 1
  for (int p = 0; p < 2; ++p) {
    // rows [ibase, ibase+32) this pass; wave covers 64 rows total
    const int ibase = blockIdx.y * 256 + wave * 64 + p * 32;

    // A fragments (R3 shape: 32 VGPRs, loaded per pass)
    short8 A[2][4];
#pragma unroll
    for (int tt = 0; tt < 2; ++tt) {
      const short* ap = (const short*)fb + (size_t)(ibase + tt * 16 + lr) * Dk + quad * 8;
#pragma unroll
      for (int kk = 0; kk < 4; ++kk) A[tt][kk] = *(const short8*)(ap + kk * 32);
    }

    // row labels (accumulator rows: row_in_tile = quad*4 + r)
    int li[2][4];
#pragma unroll
    for (int tt = 0; tt < 2; ++tt)
#pragma unroll
      for (int r = 0; r < 4; ++r)
        li[tt][r] = labels[ibase + tt * 16 + quad * 4 + r];

    float pos[2][4] = {};
    float neg[2][4] = {};

#pragma unroll
    for (int jt = 0; jt < 16; ++jt) {
      const short* bp = Bsh + (jt * 16 + lr) * Dk;
      const short8 B0 = *(const short8*)(bp + c0);
      const short8 B1 = *(const short8*)(bp + c1);
      const short8 B2 = *(const short8*)(bp + c2);
      const short8 B3 = *(const short8*)(bp + c3);

      floatx4 acc0 = {0.f, 0.f, 0.f, 0.f};
      floatx4 acc1 = {0.f, 0.f, 0.f, 0.f};
      acc0 = __builtin_amdgcn_mfma_f32_16x16x32_bf16(A[0][0], B0, acc0, 0, 0, 0);
      acc1 = __builtin_amdgcn_mfma_f32_16x16x32_bf16(A[1][0], B0, acc1, 0, 0, 0);
      acc0 = __builtin_amdgcn_mfma_f32_16x16x32_bf16(A[0][1], B1, acc0, 0, 0, 0);
      acc1 = __builtin_amdgcn_mfma_f32_16x16x32_bf16(A[1][1], B1, acc1, 0, 0, 0);
      acc0 = __builtin_amdgcn_mfma_f32_16x16x32_bf16(A[0][2], B2, acc0, 0, 0, 0);
      acc1 = __builtin_amdgcn_mfma_f32_16x16x32_bf16(A[1][2], B2, acc1, 0, 0, 0);
      acc0 = __builtin_amdgcn_mfma_f32_16x16x32_bf16(A[0][3], B3, acc0, 0, 0, 0);
      acc1 = __builtin_amdgcn_mfma_f32_16x16x32_bf16(A[1][3], B3, acc1, 0, 0, 0);

      const int j0 = jbase + jt * 16;
      const int lj = (jt & 1) ? (labj16[jt >> 1] >> 16) : (labj16[jt >> 1] & 0xffff);
      float e0, e1, e2, e3;
      // tile t=0
      e0 = __builtin_amdgcn_exp2f(__builtin_amdgcn_fmed3f(acc0[0], -CLAMP, CLAMP));
      e1 = __builtin_amdgcn_exp2f(__builtin_amdgcn_fmed3f(acc0[1], -CLAMP, CLAMP));
      e2 = __builtin_amdgcn_exp2f(__builtin_amdgcn_fmed3f(acc0[2], -CLAMP, CLAMP));
      e3 = __builtin_amdgcn_exp2f(__builtin_amdgcn_fmed3f(acc0[3], -CLAMP, CLAMP));
      if (j0 == ibase) {                 // wave-uniform: tile on diagonal
        if (dl[0]) e0 = 0.f;
        if (dl[1]) e1 = 0.f;
        if (dl[2]) e2 = 0.f;
        if (dl[3]) e3 = 0.f;
      }
      neg[0][0] += e0; neg[0][1] += e1; neg[0][2] += e2; neg[0][3] += e3;
      pos[0][0] += (li[0][0] == lj) ? e0 : 0.f;
      pos[0][1] += (li[0][1] == lj) ? e1 : 0.f;
      pos[0][2] += (li[0][2] == lj) ? e2 : 0.f;
      pos[0][3] += (li[0][3] == lj) ? e3 : 0.f;
      // tile t=1
      e0 = __builtin_amdgcn_exp2f(__builtin_amdgcn_fmed3f(acc1[0], -CLAMP, CLAMP));
      e1 = __builtin_amdgcn_exp2f(__builtin_amdgcn_fmed3f(acc1[1], -CLAMP, CLAMP));
      e2 = __builtin_amdgcn_exp2f(__builtin_amdgcn_fmed3f(acc1[2], -CLAMP, CLAMP));
      e3 = __builtin_amdgcn_exp2f(__builtin_amdgcn_fmed3f(acc1[3], -CLAMP, CLAMP));
      if (j0 == ibase + 16) {
        if (dl[0]) e0 = 0.f;
        if (dl[1]) e1 = 0.f;
        if (dl[2]) e2 = 0.f;
        if (dl[3]) e3 = 0.f;
      }
      neg[1][0] += e0; neg[1][1] += e1; neg[1][2] += e2; neg[1][3] += e3;
      pos[1][0] += (li[1][0] == lj) ? e0 : 0.f;
      pos[1][1] += (li[1][1] == lj) ? e1 : 0.f;
      pos[1][2] += (li[1][2] == lj) ? e2 : 0.f;
      pos[1][3] += (li[1][3] == lj) ? e3 : 0.f;
    }

    // reduce across the 16 lanes of a col-group (xor 1,2,4,8 stays in group);
    // unique (slice,row) writer -> plain stores, no atomics, no memset
#pragma unroll
    for (int tt = 0; tt < 2; ++tt)
#pragma unroll
      for (int r = 0; r < 4; ++r) {
        float p2 = pos[tt][r], n2 = neg[tt][r];
#pragma unroll
        for (int m = 1; m < 16; m <<= 1) {
          p2 += __shfl_xor(p2, m);
          n2 += __shfl_xor(n2, m);
        }
        if (lr == 0) {
          const int row = ibase + tt * 16 + quad * 4 + r;
          rowpos2[(size_t)blockIdx.x * Bn + row] = p2;
          rowneg2[(size_t)blockIdx.x * Bn + row] = n2;
        }
      }

    __builtin_amdgcn_sched_barrier(0);   // keep pass-1 A-loads from hoisting
  }
}

// ---- kernel 3: sum slice partials, per-row loss, mean (distributed) ------
__global__ __launch_bounds__(256) void finalize_k(
    const float* __restrict__ rowpos2, const float* __restrict__ rowneg2,
    float* __restrict__ out) {
  const int row = blockIdx.x * 256 + threadIdx.x;
  float p = 0.f, n = 0.f;
#pragma unroll
  for (int s = 0; s < NSLICE; ++s) {       // coalesced: consecutive rows adjacent
    p += rowpos2[(size_t)s * Bn + row];
    n += rowneg2[(size_t)s * Bn + row];
  }
  p = fmaxf(p, 1e-8f);
  n = fmaxf(n, 1e-8f);
  float loss = LN2 * (__builtin_amdgcn_logf(n) - __builtin_amdgcn_logf(p));
#pragma unroll
  for (int m = 1; m < 64; m <<= 1) loss += __shfl_xor(loss, m);
  __shared__ float partial[4];
  const int lane = threadIdx.x & 63, w = threadIdx.x >> 6;
  if (lane == 0) partial[w] = loss;
  __syncthreads();
  if (threadIdx.x == 0) {
    const float s = partial[0] + partial[1] + partial[2] + partial[3];
    atomicAdd(out, s * (1.0f / (float)Bn));   // out zeroed by normalize_k
  }
}

extern "C" void kernel_launch(void* const* d_in, const int* in_sizes, int n_in,
                              void* d_out, int out_size, void* d_ws, size_t ws_size,
                              hipStream_t stream) {
  const float* feat   = (const float*)d_in[0];
  const int*   labels = (const int*)d_in[1];
  float* out = (float*)d_out;

  // ws layout: [0, 2MB) bf16 fb[8192][128]; then rowpos2[32][8192], rowneg2[32][8192]
  unsigned short* fb = (unsigned short*)d_ws;
  float* rowpos2 = (float*)((char*)d_ws + (size_t)Bn * Dk * sizeof(unsigned short));
  float* rowneg2 = rowpos2 + (size_t)NSLICE * Bn;

  normalize_k<<<Bn / 4, 256, 0, stream>>>(feat, fb, out);
  dim3 grid(NSLICE, 32);  // x = j-slice, y = i-block (256 rows, two 32-row passes/wave)
  simloss_k<<<grid, 256, 0, stream>>>(fb, labels, rowpos2, rowneg2);
  finalize_k<<<Bn / 256, 256, 0, stream>>>(rowpos2, rowneg2, out);
}